// Round 1
// baseline (1337.960 us; speedup 1.0000x reference)
//
#include <hip/hip_runtime.h>
#include <math.h>

#define BATCH 4
#define SEQ   2048
#define DM    1024

constexpr int BM = 128, BN = 128, BK = 8;

// ---------------------------------------------------------------------------
// Kernel 1: fused QKV projection.  out[m,n] = sum_k x[m,k] * W[n,k] + b[n]
// (Linear with W stored [out,in] => NT GEMM; both operands contiguous in k.)
// grid = (M/128, N/128, 3), block = 256
// ---------------------------------------------------------------------------
__global__ __launch_bounds__(256) void qkv_proj(
    const float* __restrict__ x,
    const float* __restrict__ wq, const float* __restrict__ bq,
    const float* __restrict__ wk, const float* __restrict__ bk,
    const float* __restrict__ wv, const float* __restrict__ bv,
    float* __restrict__ qo, float* __restrict__ ko, float* __restrict__ vo)
{
    const int z = blockIdx.z;
    const float* __restrict__ W    = (z == 0) ? wq : (z == 1) ? wk : wv;
    const float* __restrict__ bias = (z == 0) ? bq : (z == 1) ? bk : bv;
    float* __restrict__ out        = (z == 0) ? qo : (z == 1) ? ko : vo;

    __shared__ float As[BK][BM];
    __shared__ float Bs[BK][BN];

    const int m0 = blockIdx.x * BM;
    const int n0 = blockIdx.y * BN;
    const int t  = threadIdx.x;
    const int ty = t >> 4, tx = t & 15;
    const int lrow = t >> 1, lcol = (t & 1) * 4;   // tile loads: 128 rows x 8 k

    float acc[8][8] = {};

    for (int k0 = 0; k0 < DM; k0 += BK) {
        float4 a4 = *(const float4*)(x + (size_t)(m0 + lrow) * DM + k0 + lcol);
        float4 b4 = *(const float4*)(W + (size_t)(n0 + lrow) * DM + k0 + lcol);
        __syncthreads();
        As[lcol+0][lrow] = a4.x; As[lcol+1][lrow] = a4.y;
        As[lcol+2][lrow] = a4.z; As[lcol+3][lrow] = a4.w;
        Bs[lcol+0][lrow] = b4.x; Bs[lcol+1][lrow] = b4.y;
        Bs[lcol+2][lrow] = b4.z; Bs[lcol+3][lrow] = b4.w;
        __syncthreads();
        #pragma unroll
        for (int kk = 0; kk < BK; ++kk) {
            float a[8], b[8];
            *(float4*)(a)   = *(const float4*)&As[kk][ty*8];
            *(float4*)(a+4) = *(const float4*)&As[kk][ty*8+4];
            *(float4*)(b)   = *(const float4*)&Bs[kk][tx*8];
            *(float4*)(b+4) = *(const float4*)&Bs[kk][tx*8+4];
            #pragma unroll
            for (int i = 0; i < 8; ++i)
                #pragma unroll
                for (int j = 0; j < 8; ++j)
                    acc[i][j] = fmaf(a[i], b[j], acc[i][j]);
        }
    }

    float bb[8];
    #pragma unroll
    for (int j = 0; j < 8; ++j) bb[j] = bias[n0 + tx*8 + j];
    #pragma unroll
    for (int i = 0; i < 8; ++i) {
        const int m = m0 + ty*8 + i;
        float* orow = out + (size_t)m * DM + n0 + tx*8;
        float4 r0 = make_float4(acc[i][0]+bb[0], acc[i][1]+bb[1],
                                acc[i][2]+bb[2], acc[i][3]+bb[3]);
        float4 r1 = make_float4(acc[i][4]+bb[4], acc[i][5]+bb[5],
                                acc[i][6]+bb[6], acc[i][7]+bb[7]);
        *(float4*)(orow)     = r0;
        *(float4*)(orow + 4) = r1;
    }
}

// ---------------------------------------------------------------------------
// Kernel 2: scores = q @ k^T / sqrt(D).  Per batch (blockIdx.z).
// Lower-triangle blocks only (causal): blocks with n0 > m0 exit immediately.
// grid = (SEQ/128, SEQ/128, BATCH), block = 256
// ---------------------------------------------------------------------------
__global__ __launch_bounds__(256) void qk_scores(
    const float* __restrict__ q, const float* __restrict__ k,
    float* __restrict__ sc)
{
    const int m0 = blockIdx.x * BM;
    const int n0 = blockIdx.y * BN;
    if (n0 > m0) return;                      // fully masked block
    const int b  = blockIdx.z;
    const float* __restrict__ A = q + (size_t)b * SEQ * DM;
    const float* __restrict__ B = k + (size_t)b * SEQ * DM;
    float* __restrict__ C = sc + (size_t)b * SEQ * SEQ;

    __shared__ float As[BK][BM];
    __shared__ float Bs[BK][BN];

    const int t  = threadIdx.x;
    const int ty = t >> 4, tx = t & 15;
    const int lrow = t >> 1, lcol = (t & 1) * 4;

    float acc[8][8] = {};

    for (int k0 = 0; k0 < DM; k0 += BK) {
        float4 a4 = *(const float4*)(A + (size_t)(m0 + lrow) * DM + k0 + lcol);
        float4 b4 = *(const float4*)(B + (size_t)(n0 + lrow) * DM + k0 + lcol);
        __syncthreads();
        As[lcol+0][lrow] = a4.x; As[lcol+1][lrow] = a4.y;
        As[lcol+2][lrow] = a4.z; As[lcol+3][lrow] = a4.w;
        Bs[lcol+0][lrow] = b4.x; Bs[lcol+1][lrow] = b4.y;
        Bs[lcol+2][lrow] = b4.z; Bs[lcol+3][lrow] = b4.w;
        __syncthreads();
        #pragma unroll
        for (int kk = 0; kk < BK; ++kk) {
            float a[8], bb2[8];
            *(float4*)(a)    = *(const float4*)&As[kk][ty*8];
            *(float4*)(a+4)  = *(const float4*)&As[kk][ty*8+4];
            *(float4*)(bb2)  = *(const float4*)&Bs[kk][tx*8];
            *(float4*)(bb2+4)= *(const float4*)&Bs[kk][tx*8+4];
            #pragma unroll
            for (int i = 0; i < 8; ++i)
                #pragma unroll
                for (int j = 0; j < 8; ++j)
                    acc[i][j] = fmaf(a[i], bb2[j], acc[i][j]);
        }
    }

    const float scale = 0.03125f;  // 1/sqrt(1024)
    #pragma unroll
    for (int i = 0; i < 8; ++i) {
        const int m = m0 + ty*8 + i;
        float* orow = C + (size_t)m * SEQ + n0 + tx*8;
        float4 r0 = make_float4(acc[i][0]*scale, acc[i][1]*scale,
                                acc[i][2]*scale, acc[i][3]*scale);
        float4 r1 = make_float4(acc[i][4]*scale, acc[i][5]*scale,
                                acc[i][6]*scale, acc[i][7]*scale);
        *(float4*)(orow)     = r0;
        *(float4*)(orow + 4) = r1;
    }
}

// ---------------------------------------------------------------------------
// Kernel 3: causal row softmax in place.  One block per row; row staged in LDS.
// Writes 0 for masked (j > i) entries so PV can run as a plain GEMM.
// grid = BATCH*SEQ, block = 256
// ---------------------------------------------------------------------------
__global__ __launch_bounds__(256) void softmax_causal(float* __restrict__ sc)
{
    const int row = blockIdx.x;
    const int b = row >> 11;           // /SEQ
    const int i = row & (SEQ - 1);
    float* s = sc + (size_t)b * SEQ * SEQ + (size_t)i * SEQ;

    __shared__ float buf[SEQ];
    __shared__ float red[4];
    const int t = threadIdx.x;
    const int wid = t >> 6, lane = t & 63;

    float lmax = -INFINITY;
    for (int j = t; j < SEQ; j += 256) {
        float vj = (j <= i) ? s[j] : -INFINITY;
        buf[j] = vj;
        lmax = fmaxf(lmax, vj);
    }
    #pragma unroll
    for (int o = 32; o > 0; o >>= 1) lmax = fmaxf(lmax, __shfl_xor(lmax, o));
    if (lane == 0) red[wid] = lmax;
    __syncthreads();
    const float rowmax = fmaxf(fmaxf(red[0], red[1]), fmaxf(red[2], red[3]));
    __syncthreads();

    float lsum = 0.f;
    for (int j = t; j < SEQ; j += 256) {
        float e = (j <= i) ? __expf(buf[j] - rowmax) : 0.f;
        buf[j] = e;
        lsum += e;
    }
    #pragma unroll
    for (int o = 32; o > 0; o >>= 1) lsum += __shfl_xor(lsum, o);
    if (lane == 0) red[wid] = lsum;
    __syncthreads();
    const float inv = 1.f / (red[0] + red[1] + red[2] + red[3]);

    for (int j = t; j < SEQ; j += 256) s[j] = buf[j] * inv;
}

// ---------------------------------------------------------------------------
// Kernel 4: out = attn @ v  (NN GEMM), causal K-limit (k <= m0+BM-1).
// grid = (SEQ/128, DM/128, BATCH), block = 256
// ---------------------------------------------------------------------------
__global__ __launch_bounds__(256) void pv_gemm(
    const float* __restrict__ sc, const float* __restrict__ v,
    float* __restrict__ out)
{
    const int m0 = blockIdx.x * BM;
    const int n0 = blockIdx.y * BN;
    const int b  = blockIdx.z;
    const float* __restrict__ A = sc + (size_t)b * SEQ * SEQ;
    const float* __restrict__ B = v  + (size_t)b * SEQ * DM;
    float* __restrict__ C = out + (size_t)b * SEQ * DM;

    __shared__ float As[BK][BM];
    __shared__ float Bs[BK][BN];

    const int t  = threadIdx.x;
    const int ty = t >> 4, tx = t & 15;
    const int larow = t >> 1,  lacol = (t & 1) * 4;   // A tile: 128 rows x 8 k
    const int lbrow = t >> 5,  lbcol = (t & 31) * 4;  // B tile: 8 k x 128 n

    float acc[8][8] = {};
    const int kmax = m0 + BM;   // causal: rows m0..m0+127 only need k <= m0+127

    for (int k0 = 0; k0 < kmax; k0 += BK) {
        float4 a4 = *(const float4*)(A + (size_t)(m0 + larow) * SEQ + k0 + lacol);
        float4 b4 = *(const float4*)(B + (size_t)(k0 + lbrow) * DM + n0 + lbcol);
        __syncthreads();
        As[lacol+0][larow] = a4.x; As[lacol+1][larow] = a4.y;
        As[lacol+2][larow] = a4.z; As[lacol+3][larow] = a4.w;
        *(float4*)&Bs[lbrow][lbcol] = b4;
        __syncthreads();
        #pragma unroll
        for (int kk = 0; kk < BK; ++kk) {
            float a[8], bb2[8];
            *(float4*)(a)    = *(const float4*)&As[kk][ty*8];
            *(float4*)(a+4)  = *(const float4*)&As[kk][ty*8+4];
            *(float4*)(bb2)  = *(const float4*)&Bs[kk][tx*8];
            *(float4*)(bb2+4)= *(const float4*)&Bs[kk][tx*8+4];
            #pragma unroll
            for (int i = 0; i < 8; ++i)
                #pragma unroll
                for (int j = 0; j < 8; ++j)
                    acc[i][j] = fmaf(a[i], bb2[j], acc[i][j]);
        }
    }

    #pragma unroll
    for (int i = 0; i < 8; ++i) {
        const int m = m0 + ty*8 + i;
        float* orow = C + (size_t)m * DM + n0 + tx*8;
        *(float4*)(orow)     = make_float4(acc[i][0], acc[i][1], acc[i][2], acc[i][3]);
        *(float4*)(orow + 4) = make_float4(acc[i][4], acc[i][5], acc[i][6], acc[i][7]);
    }
}

// ---------------------------------------------------------------------------
extern "C" void kernel_launch(void* const* d_in, const int* in_sizes, int n_in,
                              void* d_out, int out_size, void* d_ws, size_t ws_size,
                              hipStream_t stream)
{
    const float* x  = (const float*)d_in[0];
    const float* wq = (const float*)d_in[1];
    const float* bq = (const float*)d_in[2];
    const float* wk = (const float*)d_in[3];
    const float* bk = (const float*)d_in[4];
    const float* wv = (const float*)d_in[5];
    const float* bv = (const float*)d_in[6];
    float* out = (float*)d_out;

    // Workspace layout (floats): q | k | v | scores  = 168 MB total
    float* ws = (float*)d_ws;
    const size_t QKV = (size_t)BATCH * SEQ * DM;       // 8,388,608
    float* q  = ws;
    float* k  = ws + QKV;
    float* v  = ws + 2 * QKV;
    float* sc = ws + 3 * QKV;                          // BATCH*SEQ*SEQ floats

    dim3 gProj(BATCH * SEQ / BM, DM / BN, 3);
    qkv_proj<<<gProj, 256, 0, stream>>>(x, wq, bq, wk, bk, wv, bv, q, k, v);

    dim3 gScore(SEQ / BM, SEQ / BN, BATCH);
    qk_scores<<<gScore, 256, 0, stream>>>(q, k, sc);

    softmax_causal<<<BATCH * SEQ, 256, 0, stream>>>(sc);

    dim3 gPV(SEQ / BM, DM / BN, BATCH);
    pv_gemm<<<gPV, 256, 0, stream>>>(sc, v, out);
}

// Round 4
// 218.256 us; speedup vs baseline: 6.1302x; 6.1302x over previous
//
#include <hip/hip_runtime.h>
#include <math.h>

#define BATCH 4
#define SEQ   2048
#define DM    1024
#define NTOK  (BATCH * SEQ)   // 8192

typedef __attribute__((ext_vector_type(8))) short bf16x8;
typedef __attribute__((ext_vector_type(4))) float f32x4;
typedef unsigned short u16;
struct alignas(8) us4 { u16 x, y, z, w; };

__device__ __forceinline__ u16 f2bf(float f) {
    union { float f; unsigned u; } v; v.f = f;
    unsigned r = v.u + 0x7fffu + ((v.u >> 16) & 1u);   // round-to-nearest-even
    return (u16)(r >> 16);
}

__device__ __forceinline__ void gload_lds16(const void* g, void* l) {
    __builtin_amdgcn_global_load_lds(
        (const __attribute__((address_space(1))) unsigned int*)g,
        (__attribute__((address_space(3))) unsigned int*)l, 16, 0, 0);
}

// Stage a 128-row x 32-k bf16 tile from row-major global (ld elems) into a
// linear LDS tile [128][32]. 4 waves x 2 issues x 64 lanes x 16B = 8192 B.
// LDS dest is wave-uniform base + lane*16 (HW rule); global src is per-lane.
__device__ __forceinline__ void stage_tile(
    const u16* __restrict__ G, int ld, int row0, int kt,
    u16* lds, int wid, int lane)
{
    #pragma unroll
    for (int j = 0; j < 2; ++j) {
        const int off  = wid * 2048 + j * 1024;     // bytes, wave-uniform
        const int loff = off + lane * 16;           // this lane's dest byte
        const int row  = loff >> 6;                 // 64 B per row
        const int ke   = (loff & 63) >> 1;          // k-element offset
        gload_lds16(G + (size_t)(row0 + row) * ld + kt + ke, (char*)lds + off);
    }
}

// Per wave: 4x4 fragments of 16x16x32 over a 64x64 sub-tile.
// A-frag lane map: A[lane&15][(lane>>4)*8 + j]; B operand loaded identically
// from the [N][K] tile gives NT semantics. C/D: col=lane&15, row=(lane>>4)*4+r.
__device__ __forceinline__ void frag_mma(
    const u16* As, const u16* Bs, int wr, int wc, int lane, f32x4 acc[4][4])
{
    const int lrow = lane & 15, lk = (lane >> 4) * 8;
    bf16x8 a[4], b[4];
    #pragma unroll
    for (int i = 0; i < 4; ++i)
        a[i] = *(const bf16x8*)(As + (wr * 64 + i * 16 + lrow) * 32 + lk);
    #pragma unroll
    for (int i = 0; i < 4; ++i)
        b[i] = *(const bf16x8*)(Bs + (wc * 64 + i * 16 + lrow) * 32 + lk);
    #pragma unroll
    for (int i = 0; i < 4; ++i)
        #pragma unroll
        for (int j = 0; j < 4; ++j)
            acc[i][j] = __builtin_amdgcn_mfma_f32_16x16x32_bf16(
                a[i], b[j], acc[i][j], 0, 0, 0);
}

// ---------------------------------------------------------------------------
// f32 -> bf16 convert, float4 in / us4 out
// ---------------------------------------------------------------------------
__global__ __launch_bounds__(256) void conv_bf16(
    const float* __restrict__ in, u16* __restrict__ out, int n4)
{
    for (int i = blockIdx.x * 256 + threadIdx.x; i < n4; i += gridDim.x * 256) {
        float4 f = ((const float4*)in)[i];
        us4 p{f2bf(f.x), f2bf(f.y), f2bf(f.z), f2bf(f.w)};
        ((us4*)out)[i] = p;
    }
}

// ---------------------------------------------------------------------------
// QKV projection: NT GEMM  out[m][n] = sum_k x[m][k] W[n][k] + b[n]
// z=0 -> q bf16 [NTOK][DM], z=1 -> k bf16, z=2 -> vT bf16 [DM][NTOK]
// ---------------------------------------------------------------------------
__global__ __launch_bounds__(256) void qkv_mfma(
    const u16* __restrict__ xb,
    const u16* __restrict__ wqb, const float* __restrict__ bq,
    const u16* __restrict__ wkb, const float* __restrict__ bk,
    const u16* __restrict__ wvb, const float* __restrict__ bv,
    u16* __restrict__ qb, u16* __restrict__ kb, u16* __restrict__ vT)
{
    __shared__ u16 As[128 * 32], Bs[128 * 32];
    const int z = blockIdx.z;
    const u16* W = (z == 0) ? wqb : (z == 1) ? wkb : wvb;
    const float* bias = (z == 0) ? bq : (z == 1) ? bk : bv;
    const int m0 = blockIdx.x * 128, n0 = blockIdx.y * 128;
    const int t = threadIdx.x, wid = t >> 6, lane = t & 63;
    const int wr = wid >> 1, wc = wid & 1;

    f32x4 acc[4][4] = {};
    for (int kt = 0; kt < DM; kt += 32) {
        __syncthreads();
        stage_tile(xb, DM, m0, kt, As, wid, lane);
        stage_tile(W,  DM, n0, kt, Bs, wid, lane);
        __syncthreads();
        frag_mma(As, Bs, wr, wc, lane, acc);
    }

    const int lrow = lane & 15, lg = lane >> 4;
    if (z < 2) {
        u16* out = (z == 0) ? qb : kb;
        #pragma unroll
        for (int ni = 0; ni < 4; ++ni) {
            const int n = n0 + wc * 64 + ni * 16 + lrow;
            const float bn = bias[n];
            #pragma unroll
            for (int mi = 0; mi < 4; ++mi) {
                const int mb = m0 + wr * 64 + mi * 16 + lg * 4;
                #pragma unroll
                for (int r = 0; r < 4; ++r)
                    out[(size_t)(mb + r) * DM + n] = f2bf(acc[mi][ni][r] + bn);
            }
        }
    } else {
        #pragma unroll
        for (int ni = 0; ni < 4; ++ni) {
            const int n = n0 + wc * 64 + ni * 16 + lrow;
            const float bn = bias[n];
            #pragma unroll
            for (int mi = 0; mi < 4; ++mi) {
                const int mb = m0 + wr * 64 + mi * 16 + lg * 4;
                us4 p{f2bf(acc[mi][ni][0] + bn), f2bf(acc[mi][ni][1] + bn),
                      f2bf(acc[mi][ni][2] + bn), f2bf(acc[mi][ni][3] + bn)};
                *(us4*)(vT + (size_t)n * NTOK + mb) = p;   // transposed store
            }
        }
    }
}

// ---------------------------------------------------------------------------
// scores = q k^T / 32 (fp32 out), causal block skip (n0 > m0)
// ---------------------------------------------------------------------------
__global__ __launch_bounds__(256) void qk_mfma(
    const u16* __restrict__ qb, const u16* __restrict__ kb,
    float* __restrict__ sc)
{
    const int m0 = blockIdx.x * 128, n0 = blockIdx.y * 128;
    if (n0 > m0) return;
    __shared__ u16 As[128 * 32], Bs[128 * 32];
    const int b = blockIdx.z;
    const u16* A = qb + (size_t)b * SEQ * DM;
    const u16* B = kb + (size_t)b * SEQ * DM;
    float* C = sc + (size_t)b * SEQ * SEQ;
    const int t = threadIdx.x, wid = t >> 6, lane = t & 63;
    const int wr = wid >> 1, wc = wid & 1;

    f32x4 acc[4][4] = {};
    for (int kt = 0; kt < DM; kt += 32) {
        __syncthreads();
        stage_tile(A, DM, m0, kt, As, wid, lane);
        stage_tile(B, DM, n0, kt, Bs, wid, lane);
        __syncthreads();
        frag_mma(As, Bs, wr, wc, lane, acc);
    }
    const int lrow = lane & 15, lg = lane >> 4;
    #pragma unroll
    for (int mi = 0; mi < 4; ++mi) {
        const int mb = m0 + wr * 64 + mi * 16 + lg * 4;
        #pragma unroll
        for (int ni = 0; ni < 4; ++ni) {
            const int n = n0 + wc * 64 + ni * 16 + lrow;
            #pragma unroll
            for (int r = 0; r < 4; ++r)
                C[(size_t)(mb + r) * SEQ + n] = acc[mi][ni][r] * 0.03125f;
        }
    }
}

// ---------------------------------------------------------------------------
// causal row softmax: fp32 scores -> bf16 attn (zeros for j > i)
// ---------------------------------------------------------------------------
__global__ __launch_bounds__(256) void softmax_causal(
    const float* __restrict__ sc, u16* __restrict__ attn)
{
    const int row = blockIdx.x;
    const int b = row >> 11, i = row & (SEQ - 1);
    const float* s = sc + (size_t)b * SEQ * SEQ + (size_t)i * SEQ;
    u16* a = attn + (size_t)b * SEQ * SEQ + (size_t)i * SEQ;
    __shared__ float buf[SEQ];
    __shared__ float red[4];
    const int t = threadIdx.x, wid = t >> 6, lane = t & 63;

    float lmax = -INFINITY;
    for (int j = t; j <= i; j += 256) {
        float vj = s[j]; buf[j] = vj; lmax = fmaxf(lmax, vj);
    }
    #pragma unroll
    for (int o = 32; o > 0; o >>= 1) lmax = fmaxf(lmax, __shfl_xor(lmax, o));
    if (lane == 0) red[wid] = lmax;
    __syncthreads();
    const float rowmax = fmaxf(fmaxf(red[0], red[1]), fmaxf(red[2], red[3]));
    __syncthreads();

    float lsum = 0.f;
    for (int j = t; j <= i; j += 256) {
        float e = __expf(buf[j] - rowmax); buf[j] = e; lsum += e;
    }
    #pragma unroll
    for (int o = 32; o > 0; o >>= 1) lsum += __shfl_xor(lsum, o);
    if (lane == 0) red[wid] = lsum;
    __syncthreads();
    const float inv = 1.f / (red[0] + red[1] + red[2] + red[3]);

    for (int j = t; j < SEQ; j += 256)
        a[j] = (j <= i) ? f2bf(buf[j] * inv) : (u16)0;
}

// ---------------------------------------------------------------------------
// out = attn @ v : NT GEMM vs vT[d][tok], causal K-limit kmax = m0+128
// ---------------------------------------------------------------------------
__global__ __launch_bounds__(256) void pv_mfma(
    const u16* __restrict__ attn, const u16* __restrict__ vT,
    float* __restrict__ out)
{
    __shared__ u16 As[128 * 32], Bs[128 * 32];
    const int m0 = blockIdx.x * 128, n0 = blockIdx.y * 128;
    const int b = blockIdx.z;
    const u16* A = attn + (size_t)b * SEQ * SEQ;   // lda = SEQ
    const u16* B = vT + (size_t)b * SEQ;           // ldb = NTOK, cols of batch b
    float* C = out + (size_t)b * SEQ * DM;
    const int t = threadIdx.x, wid = t >> 6, lane = t & 63;
    const int wr = wid >> 1, wc = wid & 1;

    f32x4 acc[4][4] = {};
    const int kmax = m0 + 128;
    for (int kt = 0; kt < kmax; kt += 32) {
        __syncthreads();
        stage_tile(A, SEQ,  m0, kt, As, wid, lane);
        stage_tile(B, NTOK, n0, kt, Bs, wid, lane);
        __syncthreads();
        frag_mma(As, Bs, wr, wc, lane, acc);
    }
    const int lrow = lane & 15, lg = lane >> 4;
    #pragma unroll
    for (int mi = 0; mi < 4; ++mi) {
        const int mb = m0 + wr * 64 + mi * 16 + lg * 4;
        #pragma unroll
        for (int ni = 0; ni < 4; ++ni) {
            const int n = n0 + wc * 64 + ni * 16 + lrow;
            #pragma unroll
            for (int r = 0; r < 4; ++r)
                C[(size_t)(mb + r) * DM + n] = acc[mi][ni][r];
        }
    }
}

// ---------------------------------------------------------------------------
extern "C" void kernel_launch(void* const* d_in, const int* in_sizes, int n_in,
                              void* d_out, int out_size, void* d_ws, size_t ws_size,
                              hipStream_t stream)
{
    const float* x  = (const float*)d_in[0];
    const float* wq = (const float*)d_in[1];
    const float* bq = (const float*)d_in[2];
    const float* wk = (const float*)d_in[3];
    const float* bk = (const float*)d_in[4];
    const float* wv = (const float*)d_in[5];
    const float* bv = (const float*)d_in[6];
    float* out = (float*)d_out;

    // ws layout (u16 elems): xb | wqb | wkb | wvb | qb | kb | vT | sc(f32) | attn
    u16* ws  = (u16*)d_ws;
    u16* xb  = ws;
    u16* wqb = xb  + (size_t)NTOK * DM;
    u16* wkb = wqb + (size_t)DM * DM;
    u16* wvb = wkb + (size_t)DM * DM;
    u16* qb  = wvb + (size_t)DM * DM;
    u16* kb  = qb  + (size_t)NTOK * DM;
    u16* vT  = kb  + (size_t)NTOK * DM;        // [DM][NTOK]
    float* sc = (float*)(vT + (size_t)NTOK * DM);
    u16* attn = (u16*)(sc + (size_t)BATCH * SEQ * SEQ);

    conv_bf16<<<2048, 256, 0, stream>>>(x,  xb,  NTOK * DM / 4);
    conv_bf16<<<512,  256, 0, stream>>>(wq, wqb, DM * DM / 4);
    conv_bf16<<<512,  256, 0, stream>>>(wk, wkb, DM * DM / 4);
    conv_bf16<<<512,  256, 0, stream>>>(wv, wvb, DM * DM / 4);

    qkv_mfma<<<dim3(NTOK / 128, DM / 128, 3), 256, 0, stream>>>(
        xb, wqb, bq, wkb, bk, wvb, bv, qb, kb, vT);

    qk_mfma<<<dim3(SEQ / 128, SEQ / 128, BATCH), 256, 0, stream>>>(qb, kb, sc);

    softmax_causal<<<BATCH * SEQ, 256, 0, stream>>>(sc, attn);

    pv_mfma<<<dim3(SEQ / 128, DM / 128, BATCH), 256, 0, stream>>>(attn, vT, out);
}

// Round 5
// 207.777 us; speedup vs baseline: 6.4394x; 1.0504x over previous
//
#include <hip/hip_runtime.h>
#include <math.h>

#define BATCH 4
#define SEQ   2048
#define DM    1024
#define NTOK  (BATCH * SEQ)   // 8192

typedef __attribute__((ext_vector_type(8))) short bf16x8;
typedef __attribute__((ext_vector_type(4))) float f32x4;
typedef unsigned short u16;
struct alignas(8) us4 { u16 x, y, z, w; };

__device__ __forceinline__ u16 f2bf(float f) {
    union { float f; unsigned u; } v; v.f = f;
    unsigned r = v.u + 0x7fffu + ((v.u >> 16) & 1u);   // round-to-nearest-even
    return (u16)(r >> 16);
}

__device__ __forceinline__ void gload_lds16(const void* g, void* l) {
    __builtin_amdgcn_global_load_lds(
        (const __attribute__((address_space(1))) unsigned int*)g,
        (__attribute__((address_space(3))) unsigned int*)l, 16, 0, 0);
}

// Stage a 128-row x 32-k bf16 tile from row-major global (ld elems) into a
// linear LDS tile [128][32]. 4 waves x 2 issues x 64 lanes x 16B = 8192 B.
// LDS dest is wave-uniform base + lane*16 (HW rule); global src is per-lane.
__device__ __forceinline__ void stage_tile(
    const u16* __restrict__ G, int ld, int row0, int kt,
    u16* lds, int wid, int lane)
{
    #pragma unroll
    for (int j = 0; j < 2; ++j) {
        const int off  = wid * 2048 + j * 1024;     // bytes, wave-uniform
        const int loff = off + lane * 16;           // this lane's dest byte
        const int row  = loff >> 6;                 // 64 B per row
        const int ke   = (loff & 63) >> 1;          // k-element offset
        gload_lds16(G + (size_t)(row0 + row) * ld + kt + ke, (char*)lds + off);
    }
}

// Per wave: 4x4 fragments of 16x16x32 over a 64x64 sub-tile.
// A-frag lane map: A[lane&15][(lane>>4)*8 + j]; B operand loaded identically
// from the [N][K] tile gives NT semantics. C/D: col=lane&15, row=(lane>>4)*4+r.
__device__ __forceinline__ void frag_mma(
    const u16* As, const u16* Bs, int wr, int wc, int lane, f32x4 acc[4][4])
{
    const int lrow = lane & 15, lk = (lane >> 4) * 8;
    bf16x8 a[4], b[4];
    #pragma unroll
    for (int i = 0; i < 4; ++i)
        a[i] = *(const bf16x8*)(As + (wr * 64 + i * 16 + lrow) * 32 + lk);
    #pragma unroll
    for (int i = 0; i < 4; ++i)
        b[i] = *(const bf16x8*)(Bs + (wc * 64 + i * 16 + lrow) * 32 + lk);
    #pragma unroll
    for (int i = 0; i < 4; ++i)
        #pragma unroll
        for (int j = 0; j < 4; ++j)
            acc[i][j] = __builtin_amdgcn_mfma_f32_16x16x32_bf16(
                a[i], b[j], acc[i][j], 0, 0, 0);
}

// ---------------------------------------------------------------------------
// f32 -> bf16 convert, float4 in / us4 out
// ---------------------------------------------------------------------------
__global__ __launch_bounds__(256) void conv_bf16(
    const float* __restrict__ in, u16* __restrict__ out, int n4)
{
    for (int i = blockIdx.x * 256 + threadIdx.x; i < n4; i += gridDim.x * 256) {
        float4 f = ((const float4*)in)[i];
        us4 p{f2bf(f.x), f2bf(f.y), f2bf(f.z), f2bf(f.w)};
        ((us4*)out)[i] = p;
    }
}

// 3 weight matrices in one launch (z selects), saves 2 launch overheads
__global__ __launch_bounds__(256) void conv_bf16_w3(
    const float* __restrict__ w0, const float* __restrict__ w1,
    const float* __restrict__ w2,
    u16* __restrict__ o0, u16* __restrict__ o1, u16* __restrict__ o2)
{
    const int z = blockIdx.z;
    const float* in = (z == 0) ? w0 : (z == 1) ? w1 : w2;
    u16* out = (z == 0) ? o0 : (z == 1) ? o1 : o2;
    const int n4 = DM * DM / 4;
    for (int i = blockIdx.x * 256 + threadIdx.x; i < n4; i += gridDim.x * 256) {
        float4 f = ((const float4*)in)[i];
        us4 p{f2bf(f.x), f2bf(f.y), f2bf(f.z), f2bf(f.w)};
        ((us4*)out)[i] = p;
    }
}

// ---------------------------------------------------------------------------
// QKV projection: NT GEMM  out[m][n] = sum_k x[m][k] W[n][k] + b[n]
// z=0 -> q bf16 [NTOK][DM], z=1 -> k bf16, z=2 -> vT bf16 [DM][NTOK]
// ---------------------------------------------------------------------------
__global__ __launch_bounds__(256) void qkv_mfma(
    const u16* __restrict__ xb,
    const u16* __restrict__ wqb, const float* __restrict__ bq,
    const u16* __restrict__ wkb, const float* __restrict__ bk,
    const u16* __restrict__ wvb, const float* __restrict__ bv,
    u16* __restrict__ qb, u16* __restrict__ kb, u16* __restrict__ vT)
{
    __shared__ u16 As[128 * 32], Bs[128 * 32];
    const int z = blockIdx.z;
    const u16* W = (z == 0) ? wqb : (z == 1) ? wkb : wvb;
    const float* bias = (z == 0) ? bq : (z == 1) ? bk : bv;
    const int m0 = blockIdx.x * 128, n0 = blockIdx.y * 128;
    const int t = threadIdx.x, wid = t >> 6, lane = t & 63;
    const int wr = wid >> 1, wc = wid & 1;

    f32x4 acc[4][4] = {};
    for (int kt = 0; kt < DM; kt += 32) {
        __syncthreads();
        stage_tile(xb, DM, m0, kt, As, wid, lane);
        stage_tile(W,  DM, n0, kt, Bs, wid, lane);
        __syncthreads();
        frag_mma(As, Bs, wr, wc, lane, acc);
    }

    const int lrow = lane & 15, lg = lane >> 4;
    if (z < 2) {
        u16* out = (z == 0) ? qb : kb;
        #pragma unroll
        for (int ni = 0; ni < 4; ++ni) {
            const int n = n0 + wc * 64 + ni * 16 + lrow;
            const float bn = bias[n];
            #pragma unroll
            for (int mi = 0; mi < 4; ++mi) {
                const int mb = m0 + wr * 64 + mi * 16 + lg * 4;
                #pragma unroll
                for (int r = 0; r < 4; ++r)
                    out[(size_t)(mb + r) * DM + n] = f2bf(acc[mi][ni][r] + bn);
            }
        }
    } else {
        #pragma unroll
        for (int ni = 0; ni < 4; ++ni) {
            const int n = n0 + wc * 64 + ni * 16 + lrow;
            const float bn = bias[n];
            #pragma unroll
            for (int mi = 0; mi < 4; ++mi) {
                const int mb = m0 + wr * 64 + mi * 16 + lg * 4;
                us4 p{f2bf(acc[mi][ni][0] + bn), f2bf(acc[mi][ni][1] + bn),
                      f2bf(acc[mi][ni][2] + bn), f2bf(acc[mi][ni][3] + bn)};
                *(us4*)(vT + (size_t)n * NTOK + mb) = p;   // transposed store
            }
        }
    }
}

// ---------------------------------------------------------------------------
// scores = q k^T / 32 (fp32 out), causal block skip (n0 > m0)
// ---------------------------------------------------------------------------
__global__ __launch_bounds__(256) void qk_mfma(
    const u16* __restrict__ qb, const u16* __restrict__ kb,
    float* __restrict__ sc)
{
    const int m0 = blockIdx.x * 128, n0 = blockIdx.y * 128;
    if (n0 > m0) return;
    __shared__ u16 As[128 * 32], Bs[128 * 32];
    const int b = blockIdx.z;
    const u16* A = qb + (size_t)b * SEQ * DM;
    const u16* B = kb + (size_t)b * SEQ * DM;
    float* C = sc + (size_t)b * SEQ * SEQ;
    const int t = threadIdx.x, wid = t >> 6, lane = t & 63;
    const int wr = wid >> 1, wc = wid & 1;

    f32x4 acc[4][4] = {};
    for (int kt = 0; kt < DM; kt += 32) {
        __syncthreads();
        stage_tile(A, DM, m0, kt, As, wid, lane);
        stage_tile(B, DM, n0, kt, Bs, wid, lane);
        __syncthreads();
        frag_mma(As, Bs, wr, wc, lane, acc);
    }
    const int lrow = lane & 15, lg = lane >> 4;
    #pragma unroll
    for (int mi = 0; mi < 4; ++mi) {
        const int mb = m0 + wr * 64 + mi * 16 + lg * 4;
        #pragma unroll
        for (int ni = 0; ni < 4; ++ni) {
            const int n = n0 + wc * 64 + ni * 16 + lrow;
            #pragma unroll
            for (int r = 0; r < 4; ++r)
                C[(size_t)(mb + r) * SEQ + n] = acc[mi][ni][r] * 0.03125f;
        }
    }
}

// ---------------------------------------------------------------------------
// causal row softmax: one WAVE per row, row held entirely in registers
// (8 x float4 per lane = 2048 floats per wave). No LDS, no idle-lane tail.
// grid = BATCH*SEQ/4 blocks of 256 (4 waves = 4 rows per block).
// ---------------------------------------------------------------------------
__global__ __launch_bounds__(256) void softmax_rows(
    const float* __restrict__ sc, u16* __restrict__ attn)
{
    const int row  = blockIdx.x * 4 + (threadIdx.x >> 6);
    const int lane = threadIdx.x & 63;
    const int b = row >> 11, i = row & (SEQ - 1);
    const float* s = sc + (size_t)b * SEQ * SEQ + (size_t)i * SEQ;
    u16* a = attn + (size_t)b * SEQ * SEQ + (size_t)i * SEQ;

    const int nch = (i >> 8) + 1;          // chunks containing any j <= i
    float4 v[8];
    float lmax = -INFINITY;
    #pragma unroll
    for (int c = 0; c < 8; ++c) {
        if (c < nch) {
            v[c] = ((const float4*)s)[c * 64 + lane];
            const int j0 = c * 256 + lane * 4;
            if (j0 + 0 > i) v[c].x = -INFINITY;
            if (j0 + 1 > i) v[c].y = -INFINITY;
            if (j0 + 2 > i) v[c].z = -INFINITY;
            if (j0 + 3 > i) v[c].w = -INFINITY;
            lmax = fmaxf(lmax,
                   fmaxf(fmaxf(v[c].x, v[c].y), fmaxf(v[c].z, v[c].w)));
        }
    }
    #pragma unroll
    for (int o = 32; o > 0; o >>= 1) lmax = fmaxf(lmax, __shfl_xor(lmax, o));

    float lsum = 0.f;
    #pragma unroll
    for (int c = 0; c < 8; ++c) {
        if (c < nch) {
            v[c].x = __expf(v[c].x - lmax);   // exp(-inf - m) = 0 for masked
            v[c].y = __expf(v[c].y - lmax);
            v[c].z = __expf(v[c].z - lmax);
            v[c].w = __expf(v[c].w - lmax);
            lsum += (v[c].x + v[c].y) + (v[c].z + v[c].w);
        }
    }
    #pragma unroll
    for (int o = 32; o > 0; o >>= 1) lsum += __shfl_xor(lsum, o);
    const float inv = 1.f / lsum;

    #pragma unroll
    for (int c = 0; c < 8; ++c) {
        us4 p;
        if (c < nch) {
            p.x = f2bf(v[c].x * inv); p.y = f2bf(v[c].y * inv);
            p.z = f2bf(v[c].z * inv); p.w = f2bf(v[c].w * inv);
        } else {
            p.x = 0; p.y = 0; p.z = 0; p.w = 0;
        }
        ((us4*)a)[c * 64 + lane] = p;
    }
}

// ---------------------------------------------------------------------------
// out = attn @ v : NT GEMM vs vT[d][tok], causal K-limit kmax = m0+128
// ---------------------------------------------------------------------------
__global__ __launch_bounds__(256) void pv_mfma(
    const u16* __restrict__ attn, const u16* __restrict__ vT,
    float* __restrict__ out)
{
    __shared__ u16 As[128 * 32], Bs[128 * 32];
    const int m0 = blockIdx.x * 128, n0 = blockIdx.y * 128;
    const int b = blockIdx.z;
    const u16* A = attn + (size_t)b * SEQ * SEQ;   // lda = SEQ
    const u16* B = vT + (size_t)b * SEQ;           // ldb = NTOK, cols of batch b
    float* C = out + (size_t)b * SEQ * DM;
    const int t = threadIdx.x, wid = t >> 6, lane = t & 63;
    const int wr = wid >> 1, wc = wid & 1;

    f32x4 acc[4][4] = {};
    const int kmax = m0 + 128;
    for (int kt = 0; kt < kmax; kt += 32) {
        __syncthreads();
        stage_tile(A, SEQ,  m0, kt, As, wid, lane);
        stage_tile(B, NTOK, n0, kt, Bs, wid, lane);
        __syncthreads();
        frag_mma(As, Bs, wr, wc, lane, acc);
    }
    const int lrow = lane & 15, lg = lane >> 4;
    #pragma unroll
    for (int mi = 0; mi < 4; ++mi) {
        const int mb = m0 + wr * 64 + mi * 16 + lg * 4;
        #pragma unroll
        for (int ni = 0; ni < 4; ++ni) {
            const int n = n0 + wc * 64 + ni * 16 + lrow;
            #pragma unroll
            for (int r = 0; r < 4; ++r)
                C[(size_t)(mb + r) * DM + n] = acc[mi][ni][r];
        }
    }
}

// ---------------------------------------------------------------------------
extern "C" void kernel_launch(void* const* d_in, const int* in_sizes, int n_in,
                              void* d_out, int out_size, void* d_ws, size_t ws_size,
                              hipStream_t stream)
{
    const float* x  = (const float*)d_in[0];
    const float* wq = (const float*)d_in[1];
    const float* bq = (const float*)d_in[2];
    const float* wk = (const float*)d_in[3];
    const float* bk = (const float*)d_in[4];
    const float* wv = (const float*)d_in[5];
    const float* bv = (const float*)d_in[6];
    float* out = (float*)d_out;

    // ws layout (u16 elems): xb | wqb | wkb | wvb | qb | kb | vT | sc(f32) | attn
    u16* ws  = (u16*)d_ws;
    u16* xb  = ws;
    u16* wqb = xb  + (size_t)NTOK * DM;
    u16* wkb = wqb + (size_t)DM * DM;
    u16* wvb = wkb + (size_t)DM * DM;
    u16* qb  = wvb + (size_t)DM * DM;
    u16* kb  = qb  + (size_t)NTOK * DM;
    u16* vT  = kb  + (size_t)NTOK * DM;        // [DM][NTOK]
    float* sc = (float*)(vT + (size_t)NTOK * DM);
    u16* attn = (u16*)(sc + (size_t)BATCH * SEQ * SEQ);

    conv_bf16<<<2048, 256, 0, stream>>>(x, xb, NTOK * DM / 4);
    conv_bf16_w3<<<dim3(512, 1, 3), 256, 0, stream>>>(
        wq, wk, wv, wqb, wkb, wvb);

    qkv_mfma<<<dim3(NTOK / 128, DM / 128, 3), 256, 0, stream>>>(
        xb, wqb, bq, wkb, bk, wvb, bv, qb, kb, vT);

    qk_mfma<<<dim3(SEQ / 128, SEQ / 128, BATCH), 256, 0, stream>>>(qb, kb, sc);

    softmax_rows<<<BATCH * SEQ / 4, 256, 0, stream>>>(sc, attn);

    pv_mfma<<<dim3(SEQ / 128, DM / 128, BATCH), 256, 0, stream>>>(attn, vT, out);
}